// Round 9
// baseline (228.851 us; speedup 1.0000x reference)
//
#include <hip/hip_runtime.h>
#include <hip/hip_bf16.h>

#define N_PTS  4096
#define NB     9
#define C      256
#define MID    64
#define KNBR   16
#define NROWS  (N_PTS * NB)          // 36864

typedef __attribute__((ext_vector_type(8))) short          short8;  // 8 bf16 (A/B frag)
typedef __attribute__((ext_vector_type(4))) float          f32x4;   // C/D frag
typedef __attribute__((ext_vector_type(4))) unsigned short ush4;
typedef __attribute__((ext_vector_type(8))) unsigned short ush8;

static __device__ __forceinline__ unsigned short f2bf(float f) {
    union { __hip_bfloat16 h; unsigned short u; } cv;
    cv.h = __float2bfloat16(f);          // RNE
    return cv.u;
}
static __device__ __forceinline__ float bf2f(unsigned short s) {
    union { unsigned u; float f; } v; v.u = ((unsigned)s) << 16;
    return v.f;
}
static __device__ __forceinline__ unsigned packbf(float a, float b) {
    return (unsigned)f2bf(a) | ((unsigned)f2bf(b) << 16);
}

// ---------------------------------------------------------------------------
// Kernel 1: h(bf16) = s_feats(f32) @ W_proj(f32).  M=36864 K=256 N=256.
#define LDK 40            // 32 + 8 pad (ushorts); row stride 80B, 16B aligned
__global__ __launch_bounds__(256) void k_proj(const float* __restrict__ A,
                                              const float* __restrict__ W,
                                              unsigned short* __restrict__ H) {
    __shared__ unsigned short As[128 * LDK];
    __shared__ unsigned short Bs[128 * LDK];
    const int tid = threadIdx.x;
    const int r0  = blockIdx.x * 128;
    const int n0  = blockIdx.y * 128;
    const int wave = tid >> 6, lane = tid & 63;
    const int wm = wave >> 1, wn = wave & 1;
    const int lr = lane & 15, lg = lane >> 4;

    f32x4 acc[4][4];
#pragma unroll
    for (int a = 0; a < 4; ++a)
#pragma unroll
        for (int b = 0; b < 4; ++b) acc[a][b] = (f32x4){0.f, 0.f, 0.f, 0.f};

    for (int k0 = 0; k0 < C; k0 += 32) {
        __syncthreads();
#pragma unroll
        for (int rep = 0; rep < 4; ++rep) {
            const int e   = rep * 256 + tid;      // float4 unit, 8 per row
            const int row = e >> 3;
            const int c4  = (e & 7) << 2;
            const float4 v = *reinterpret_cast<const float4*>(&A[(size_t)(r0 + row) * C + k0 + c4]);
            ush4 s = { f2bf(v.x), f2bf(v.y), f2bf(v.z), f2bf(v.w) };
            *reinterpret_cast<ush4*>(&As[row * LDK + c4]) = s;
        }
#pragma unroll
        for (int rep = 0; rep < 4; ++rep) {
            const int e = rep * 256 + tid;        // float4 unit, 32 per k-row
            const int k = e >> 5;
            const int j = (e & 31) << 2;
            const float4 v = *reinterpret_cast<const float4*>(&W[(size_t)(k0 + k) * C + n0 + j]);
            Bs[(j + 0) * LDK + k] = f2bf(v.x);
            Bs[(j + 1) * LDK + k] = f2bf(v.y);
            Bs[(j + 2) * LDK + k] = f2bf(v.z);
            Bs[(j + 3) * LDK + k] = f2bf(v.w);
        }
        __syncthreads();

        short8 af[4], bfr[4];
#pragma unroll
        for (int mf = 0; mf < 4; ++mf)
            af[mf] = *reinterpret_cast<const short8*>(&As[(wm * 64 + mf * 16 + lr) * LDK + lg * 8]);
#pragma unroll
        for (int nf = 0; nf < 4; ++nf)
            bfr[nf] = *reinterpret_cast<const short8*>(&Bs[(wn * 64 + nf * 16 + lr) * LDK + lg * 8]);
#pragma unroll
        for (int mf = 0; mf < 4; ++mf)
#pragma unroll
            for (int nf = 0; nf < 4; ++nf)
                acc[mf][nf] = __builtin_amdgcn_mfma_f32_16x16x32_bf16(af[mf], bfr[nf], acc[mf][nf], 0, 0, 0);
    }
#pragma unroll
    for (int mf = 0; mf < 4; ++mf)
#pragma unroll
        for (int nf = 0; nf < 4; ++nf) {
            const int col = n0 + wn * 64 + nf * 16 + lr;
#pragma unroll
            for (int r = 0; r < 4; ++r) {
                const int row = r0 + wm * 64 + mf * 16 + lg * 4 + r;
                H[(size_t)row * C + col] = f2bf(acc[mf][nf][r]);
            }
        }
}

// ---------------------------------------------------------------------------
// Kernel 2a: w_all[n][o][ki] (bf16, [16][160], zero-padded) for all points.
// w[ki,o] = sum_j sh[kk][j] * cg[ii*81 + j*9 + o],  ki = kk*9 + ii.
__global__ __launch_bounds__(256) void k_w(const float* __restrict__ pts,
                                           const float* __restrict__ cg,
                                           const int*   __restrict__ nbr,
                                           unsigned short* __restrict__ w_all) {
    __shared__ float cg_s[729];
    __shared__ float sh_s[KNBR][NB];
    const int tid = threadIdx.x;
    const int n   = blockIdx.x;

    for (int e = tid; e < 729; e += 256) cg_s[e] = cg[e];
    if (tid < KNBR) {
        const int idx = nbr[n * KNBR + tid];
        const float px = pts[idx * 3 + 0] - pts[n * 3 + 0];
        const float py = pts[idx * 3 + 1] - pts[n * 3 + 1];
        const float pz = pts[idx * 3 + 2] - pts[n * 3 + 2];
        const float r  = sqrtf(px * px + py * py + pz * pz);
        const float iv = 1.f / (r + 1e-8f);
        const float dx = px * iv, dy = py * iv, dz = pz * iv;
        const float c1 = 0.4886025119029199f;
        const float c2 = 1.0925484305920792f;
        sh_s[tid][0] = 0.28209479177387814f;
        sh_s[tid][1] = c1 * dy;
        sh_s[tid][2] = c1 * dz;
        sh_s[tid][3] = c1 * dx;
        sh_s[tid][4] = c2 * dx * dy;
        sh_s[tid][5] = c2 * dy * dz;
        sh_s[tid][6] = 0.31539156525252005f * (3.f * dz * dz - 1.f);
        sh_s[tid][7] = c2 * dx * dz;
        sh_s[tid][8] = 0.5462742152960396f * (dx * dx - dy * dy);
    }
    __syncthreads();

#pragma unroll
    for (int it = 0; it < 10; ++it) {
        const int t  = it * 256 + tid;      // 2560 = 16 o x 160 ki
        const int o  = t / 160;
        const int ki = t - o * 160;
        float s = 0.f;
        if (o < 9 && ki < 144) {
            const int kk = ki / 9;
            const int ii = ki - kk * 9;
#pragma unroll
            for (int j = 0; j < 9; ++j) s = fmaf(sh_s[kk][j], cg_s[ii * 81 + j * 9 + o], s);
        }
        w_all[(size_t)n * 2560 + t] = f2bf(s);
    }
}

// ---------------------------------------------------------------------------
// Kernel 2b: CG contraction via MFMA, single-stage, per c-half.
// Block bid: n = bid>>1, half = bid&1 (c0 = half*128). 4 waves.
// D[o, c_local] = sum_ki w[ki,o] * h[gather(ki)][c0+c_local],
// M=16(9), N=128, K=160(144; cols 144..167 zeroed, wT zero-padded).
//   A: wTl[16][168] from w_all (coalesced b128 stage).
//   B: Bs[128][168] [c][ki], staged ONCE: 9 gather ush8 loads/thread,
//      scalar b16 transpose writes with e^cseg bank swizzle.
// Epilogue: D + s_feats -> Xb (bf16) + per-half LN partial sums -> scr.
__global__ __launch_bounds__(256) void k_cg(const unsigned short* __restrict__ Hb,
                                            const float* __restrict__ s_feats,
                                            const unsigned short* __restrict__ w_all,
                                            const int*   __restrict__ nbr,
                                            unsigned short* __restrict__ Xb,
                                            float* __restrict__ scr) {
    __shared__ unsigned short Bs[128 * 168];     // 43008 B
    __shared__ unsigned short wTl[16 * 168];     // 5376 B
    __shared__ int idx_s[KNBR];

    const int tid  = threadIdx.x;
    const int bid  = blockIdx.x;
    const int n    = bid >> 1;
    const int half = bid & 1;
    const int c0   = half * 128;
    const int wv   = tid >> 6;
    const int lane = tid & 63;
    const int g16  = lane >> 4;
    const int l16  = lane & 15;

    if (tid < KNBR) idx_s[tid] = nbr[n * KNBR + tid];
    __syncthreads();

    // ---- issue all gather loads (thread = (cseg, kk); rows i=0..8 of nbr kk) ----
    const int cseg = tid & 15;          // 16 segs x 8 c
    const int kk   = tid >> 4;          // neighbor index
    const unsigned short* hb = Hb + (size_t)idx_s[kk] * (NB * C) + c0 + cseg * 8;
    ush8 q[9];
#pragma unroll
    for (int j = 0; j < 9; ++j)
        q[j] = *reinterpret_cast<const ush8*>(hb + (size_t)j * C);

    // ---- stage A (w_all -> wTl), coalesced, repadded 160 -> 168 ----
    {
        const int u  = tid;                       // units 0..255
        const int o  = u / 20, p = u - o * 20;
        const ush8 wv8 = *reinterpret_cast<const ush8*>(w_all + (size_t)n * 2560 + o * 160 + p * 8);
        *reinterpret_cast<ush8*>(&wTl[o * 168 + p * 8]) = wv8;
        if (tid < 64) {
            const int u2 = 256 + tid;             // units 256..319
            const int o2 = u2 / 20, p2 = u2 - o2 * 20;
            const ush8 w2 = *reinterpret_cast<const ush8*>(w_all + (size_t)n * 2560 + o2 * 160 + p2 * 8);
            *reinterpret_cast<ush8*>(&wTl[o2 * 168 + p2 * 8]) = w2;
        }
    }
    // ---- zero B cols 144..167 (stale-LDS / NaN guard for the k-pad) ----
    if (tid < 128) {
        const ush8 z = (ush8){0, 0, 0, 0, 0, 0, 0, 0};
        *reinterpret_cast<ush8*>(&Bs[tid * 168 + 144]) = z;
        *reinterpret_cast<ush8*>(&Bs[tid * 168 + 152]) = z;
        *reinterpret_cast<ush8*>(&Bs[tid * 168 + 160]) = z;
    }
    // ---- transpose-write gathered rows: B[c_local][ki], ki = kk*9 + j ----
#pragma unroll
    for (int j = 0; j < 9; ++j) {
        const unsigned short* qe = reinterpret_cast<const unsigned short*>(&q[j]);
        const int colk = kk * 9 + j;
#pragma unroll
        for (int e = 0; e < 8; ++e) {
            const int ee = e ^ (cseg & 7);        // bank-spread swizzle (bijective)
            Bs[(cseg * 8 + ee) * 168 + colk] = qe[ee];
        }
    }
    __syncthreads();

    // ---- MFMA: 5 k-steps, no restaging; wave owns 2 n-tiles ----
    f32x4 acc[2];
    acc[0] = (f32x4){0.f, 0.f, 0.f, 0.f};
    acc[1] = (f32x4){0.f, 0.f, 0.f, 0.f};
#pragma unroll
    for (int cc = 0; cc < 5; ++cc) {
        const short8 af = *reinterpret_cast<const short8*>(&wTl[l16 * 168 + cc * 32 + g16 * 8]);
        const short8 b0 = *reinterpret_cast<const short8*>(&Bs[(wv * 32 + l16) * 168 + cc * 32 + g16 * 8]);
        const short8 b1 = *reinterpret_cast<const short8*>(&Bs[(wv * 32 + 16 + l16) * 168 + cc * 32 + g16 * 8]);
        acc[0] = __builtin_amdgcn_mfma_f32_16x16x32_bf16(af, b0, acc[0], 0, 0, 0);
        acc[1] = __builtin_amdgcn_mfma_f32_16x16x32_bf16(af, b1, acc[1], 0, 0, 0);
    }

    // ---- epilogue: D -> LDS, residual, partial LN sums, Xb write ----
    __syncthreads();                     // all Bs reads done before reuse
    float* const Dld = reinterpret_cast<float*>(Bs);   // [9][132] f32
#pragma unroll
    for (int tt = 0; tt < 2; ++tt) {
        const int cl = wv * 32 + tt * 16 + l16;
#pragma unroll
        for (int rr = 0; rr < 4; ++rr) {
            const int o = g16 * 4 + rr;  // m89: col=lane&15, row=(lane>>4)*4+reg
            if (o < 9) Dld[o * 132 + cl] = acc[tt][rr] * (1.f / (float)KNBR);
        }
    }
    __syncthreads();

    if (tid < 64) {
        const int cl = tid * 2;
        const float* sf = s_feats + (size_t)n * (NB * C) + c0 + cl;
        float2 xv[9];
#pragma unroll
        for (int i = 0; i < 9; ++i) {
            xv[i].x = Dld[i * 132 + cl]     + sf[(size_t)i * C];
            xv[i].y = Dld[i * 132 + cl + 1] + sf[(size_t)i * C + 1];
        }
        float s0 = xv[0].x + xv[0].y;
        float s1 = xv[0].x * xv[0].x + xv[0].y * xv[0].y;
        float s2 = 0.f, s3 = 0.f;
#pragma unroll
        for (int o = 1; o < 4; ++o) s2 += xv[o].x * xv[o].x + xv[o].y * xv[o].y;
#pragma unroll
        for (int o = 4; o < 9; ++o) s3 += xv[o].x * xv[o].x + xv[o].y * xv[o].y;
#pragma unroll
        for (int off = 32; off >= 1; off >>= 1) {
            s0 += __shfl_xor(s0, off);
            s1 += __shfl_xor(s1, off);
            s2 += __shfl_xor(s2, off);
            s3 += __shfl_xor(s3, off);
        }
        unsigned* xo = reinterpret_cast<unsigned*>(Xb + (size_t)n * (NB * C) + c0);
#pragma unroll
        for (int i = 0; i < 9; ++i) xo[i * 128 + tid] = packbf(xv[i].x, xv[i].y);
        if (tid == 0) {
            float* sp = scr + (size_t)n * 8 + half * 4;
            sp[0] = s0; sp[1] = s1; sp[2] = s2; sp[3] = s3;
        }
    }
}

// ---------------------------------------------------------------------------
// Kernel 3: z(bf16) = LN(x) @ W_ff1.  LN fused into A-staging using scr stats.
__global__ __launch_bounds__(256) void k_ff1(const unsigned short* __restrict__ Xb,
                                             const float* __restrict__ scr,
                                             const float* __restrict__ ln_w,
                                             const float* __restrict__ ln_b,
                                             const float* __restrict__ W1,
                                             unsigned short* __restrict__ Zb) {
    __shared__ unsigned short As[128 * LDK];
    __shared__ unsigned short Bs[64 * LDK];
    const int tid = threadIdx.x;
    const int r0  = blockIdx.x * 128;
    const int wave = tid >> 6, lane = tid & 63;
    const int wm = wave >> 1, wn = wave & 1;
    const int lr = lane & 15, lg = lane >> 4;

    // per-rep row LN stats (rows fixed per thread across k0 chunks)
    float mu_[4], rv_[4];
    int   cls_[4];
#pragma unroll
    for (int rep = 0; rep < 4; ++rep) {
        const int row = r0 + ((rep * 256 + tid) >> 3);
        const int nn  = row / 9;
        const int ii  = row - nn * 9;
        const float* sp = scr + (size_t)nn * 8;
        const float a0 = sp[0] + sp[4], a1 = sp[1] + sp[5];
        const float a2 = sp[2] + sp[6], a3 = sp[3] + sp[7];
        if (ii == 0) {
            const float mu = a0 * (1.f / 256.f);
            mu_[rep] = mu;
            rv_[rep] = rsqrtf(a1 * (1.f / 256.f) - mu * mu + 1e-5f);
            cls_[rep] = 0;
        } else if (ii < 4) {
            mu_[rep] = 0.f; rv_[rep] = rsqrtf(a2 * (1.f / 768.f) + 1e-5f); cls_[rep] = 1;
        } else {
            mu_[rep] = 0.f; rv_[rep] = rsqrtf(a3 * (1.f / 1280.f) + 1e-5f); cls_[rep] = 2;
        }
    }

    f32x4 acc[4][2];
#pragma unroll
    for (int a = 0; a < 4; ++a) { acc[a][0] = (f32x4){0.f,0.f,0.f,0.f}; acc[a][1] = (f32x4){0.f,0.f,0.f,0.f}; }

    for (int k0 = 0; k0 < C; k0 += 32) {
        __syncthreads();
#pragma unroll
        for (int rep = 0; rep < 4; ++rep) {
            const int e   = rep * 256 + tid;     // ush4 unit, 8 per row
            const int row = e >> 3;
            const int c4  = (e & 7) << 2;
            const ush4 xq = *reinterpret_cast<const ush4*>(&Xb[(size_t)(r0 + row) * C + k0 + c4]);
            const float4 lw = *reinterpret_cast<const float4*>(&ln_w[cls_[rep] * C + k0 + c4]);
            const float mu = mu_[rep], rv = rv_[rep];
            float yx = (bf2f(xq.x) - mu) * rv * lw.x;
            float yy = (bf2f(xq.y) - mu) * rv * lw.y;
            float yz = (bf2f(xq.z) - mu) * rv * lw.z;
            float yw = (bf2f(xq.w) - mu) * rv * lw.w;
            if (cls_[rep] == 0) {
                const float4 lb = *reinterpret_cast<const float4*>(&ln_b[k0 + c4]);
                yx += lb.x; yy += lb.y; yz += lb.z; yw += lb.w;
            }
            ush4 s = { f2bf(yx), f2bf(yy), f2bf(yz), f2bf(yw) };
            *reinterpret_cast<ush4*>(&As[row * LDK + c4]) = s;
        }
#pragma unroll
        for (int rep = 0; rep < 2; ++rep) {
            const int e = rep * 256 + tid;       // float4 unit, 16 per k-row (64 n)
            const int k = e >> 4;
            const int j = (e & 15) << 2;
            const float4 v = *reinterpret_cast<const float4*>(&W1[(size_t)(k0 + k) * MID + j]);
            Bs[(j + 0) * LDK + k] = f2bf(v.x);
            Bs[(j + 1) * LDK + k] = f2bf(v.y);
            Bs[(j + 2) * LDK + k] = f2bf(v.z);
            Bs[(j + 3) * LDK + k] = f2bf(v.w);
        }
        __syncthreads();

        short8 af[4], bfr[2];
#pragma unroll
        for (int mf = 0; mf < 4; ++mf)
            af[mf] = *reinterpret_cast<const short8*>(&As[(wm * 64 + mf * 16 + lr) * LDK + lg * 8]);
#pragma unroll
        for (int nf = 0; nf < 2; ++nf)
            bfr[nf] = *reinterpret_cast<const short8*>(&Bs[(wn * 32 + nf * 16 + lr) * LDK + lg * 8]);
#pragma unroll
        for (int mf = 0; mf < 4; ++mf)
#pragma unroll
            for (int nf = 0; nf < 2; ++nf)
                acc[mf][nf] = __builtin_amdgcn_mfma_f32_16x16x32_bf16(af[mf], bfr[nf], acc[mf][nf], 0, 0, 0);
    }
#pragma unroll
    for (int mf = 0; mf < 4; ++mf)
#pragma unroll
        for (int nf = 0; nf < 2; ++nf) {
            const int col = wn * 32 + nf * 16 + lr;
#pragma unroll
            for (int r = 0; r < 4; ++r) {
                const int row = r0 + wm * 64 + mf * 16 + lg * 4 + r;
                Zb[(size_t)row * MID + col] = f2bf(acc[mf][nf][r]);
            }
        }
}

// ---------------------------------------------------------------------------
// Kernel 4: gate head. after = z0 @ W_gate; G[n][0:64]=silu, [64:192]=sigmoid.
__global__ __launch_bounds__(192) void k_gate(const unsigned short* __restrict__ Zb,
                                              const float* __restrict__ Wg,
                                              float* __restrict__ G) {
    __shared__ float wgs[64 * 192];
    __shared__ float z0s[16 * 64];
    const int tid = threadIdx.x;
    const int n0  = blockIdx.x * 16;

    for (int e = tid; e < 64 * 192; e += 192) wgs[e] = Wg[e];
    for (int e = tid; e < 16 * 64; e += 192) {
        const int r = e >> 6, m = e & 63;
        z0s[e] = bf2f(Zb[(size_t)(n0 + r) * (NB * MID) + m]);
    }
    __syncthreads();

    const int j = tid;
    for (int r = 0; r < 16; ++r) {
        float acc = 0.f;
        for (int m0 = 0; m0 < 64; m0 += 4) {
            const float4 zv = *reinterpret_cast<const float4*>(&z0s[r * 64 + m0]);
            acc = fmaf(zv.x, wgs[(m0 + 0) * 192 + j], acc);
            acc = fmaf(zv.y, wgs[(m0 + 1) * 192 + j], acc);
            acc = fmaf(zv.z, wgs[(m0 + 2) * 192 + j], acc);
            acc = fmaf(zv.w, wgs[(m0 + 3) * 192 + j], acc);
        }
        const float sig = 1.f / (1.f + expf(-acc));
        G[(size_t)(n0 + r) * 192 + j] = (j < 64) ? acc * sig : sig;
    }
}

// ---------------------------------------------------------------------------
// Kernel 5: out(f32) = gated(z) @ W_ff2 + x.  M=36864 K=64 N=256.
#define LDK64 72          // 64 + 8 pad; row stride 144B, 16B aligned
__global__ __launch_bounds__(256) void k_final(const unsigned short* __restrict__ Zb,
                                               const float* __restrict__ G,
                                               const float* __restrict__ W2,
                                               const unsigned short* __restrict__ Xb,
                                               float* __restrict__ OUT) {
    __shared__ unsigned short As[128 * LDK64];
    __shared__ unsigned short Bs[128 * LDK64];
    const int tid = threadIdx.x;
    const int r0  = blockIdx.x * 128;
    const int n0  = blockIdx.y * 128;
    const int wave = tid >> 6, lane = tid & 63;
    const int wm = wave >> 1, wn = wave & 1;
    const int lr = lane & 15, lg = lane >> 4;

    // stage A: gated-z rows (2 threads per row, 32 k each)
    {
        const int arow = tid >> 1;
        const int kh   = (tid & 1) * 32;
        const int grow = r0 + arow;
        const int nn   = grow / 9;
        const int ii   = grow - nn * 9;
        if (ii == 0) {
            const float* gp = &G[(size_t)nn * 192 + kh];
#pragma unroll
            for (int j = 0; j < 32; j += 4) {
                const float4 g = *reinterpret_cast<const float4*>(&gp[j]);
                ush4 s = { f2bf(g.x), f2bf(g.y), f2bf(g.z), f2bf(g.w) };
                *reinterpret_cast<ush4*>(&As[arow * LDK64 + kh + j]) = s;
            }
        } else {
            const float* gm = &G[(size_t)nn * 192 + ((ii < 4) ? 64 : 128) + kh];
            const unsigned short* zr = &Zb[(size_t)nn * (NB * MID) + ii * MID + kh];
#pragma unroll
            for (int j = 0; j < 32; j += 4) {
                const ush4 zv = *reinterpret_cast<const ush4*>(&zr[j]);
                const float4 g = *reinterpret_cast<const float4*>(&gm[j]);
                ush4 s = { f2bf(bf2f(zv.x) * g.x), f2bf(bf2f(zv.y) * g.y),
                           f2bf(bf2f(zv.z) * g.z), f2bf(bf2f(zv.w) * g.w) };
                *reinterpret_cast<ush4*>(&As[arow * LDK64 + kh + j]) = s;
            }
        }
    }
    // stage B: Bs[n][k] = W2[k][n0+n], full 64 x 128 tile
#pragma unroll
    for (int rep = 0; rep < 8; ++rep) {
        const int e = rep * 256 + tid;           // float4 unit, 32 per k-row
        const int k = e >> 5;
        const int j = (e & 31) << 2;
        const float4 v = *reinterpret_cast<const float4*>(&W2[(size_t)k * C + n0 + j]);
        Bs[(j + 0) * LDK64 + k] = f2bf(v.x);
        Bs[(j + 1) * LDK64 + k] = f2bf(v.y);
        Bs[(j + 2) * LDK64 + k] = f2bf(v.z);
        Bs[(j + 3) * LDK64 + k] = f2bf(v.w);
    }
    __syncthreads();

    f32x4 acc[4][4];
#pragma unroll
    for (int a = 0; a < 4; ++a)
#pragma unroll
        for (int b = 0; b < 4; ++b) acc[a][b] = (f32x4){0.f, 0.f, 0.f, 0.f};

#pragma unroll
    for (int ks = 0; ks < 2; ++ks) {
        short8 af[4], bfr[4];
#pragma unroll
        for (int mf = 0; mf < 4; ++mf)
            af[mf] = *reinterpret_cast<const short8*>(&As[(wm * 64 + mf * 16 + lr) * LDK64 + ks * 32 + lg * 8]);
#pragma unroll
        for (int nf = 0; nf < 4; ++nf)
            bfr[nf] = *reinterpret_cast<const short8*>(&Bs[(wn * 64 + nf * 16 + lr) * LDK64 + ks * 32 + lg * 8]);
#pragma unroll
        for (int mf = 0; mf < 4; ++mf)
#pragma unroll
            for (int nf = 0; nf < 4; ++nf)
                acc[mf][nf] = __builtin_amdgcn_mfma_f32_16x16x32_bf16(af[mf], bfr[nf], acc[mf][nf], 0, 0, 0);
    }

#pragma unroll
    for (int mf = 0; mf < 4; ++mf)
#pragma unroll
        for (int nf = 0; nf < 4; ++nf) {
            const int col = n0 + wn * 64 + nf * 16 + lr;
#pragma unroll
            for (int r = 0; r < 4; ++r) {
                const int row = r0 + wm * 64 + mf * 16 + lg * 4 + r;
                OUT[(size_t)row * C + col] = acc[mf][nf][r] + bf2f(Xb[(size_t)row * C + col]);
            }
        }
}

// ---------------------------------------------------------------------------
extern "C" void kernel_launch(void* const* d_in, const int* in_sizes, int n_in,
                              void* d_out, int out_size, void* d_ws, size_t ws_size,
                              hipStream_t stream) {
    const float* s_feats = (const float*)d_in[0];
    const float* s_pts   = (const float*)d_in[1];
    const float* cg      = (const float*)d_in[2];
    const float* W_proj  = (const float*)d_in[3];
    const float* ln_w    = (const float*)d_in[4];
    const float* ln_b    = (const float*)d_in[5];
    const float* W_ff1   = (const float*)d_in[6];
    const float* W_gate  = (const float*)d_in[7];
    const float* W_ff2   = (const float*)d_in[8];
    const int*   nbr     = (const int*)d_in[9];
    float* out = (float*)d_out;

    // workspace layout (~67 MB)
    unsigned short* Hb    = (unsigned short*)d_ws;         // NROWS*C bf16
    unsigned short* Xb    = Hb + (size_t)NROWS * C;        // NROWS*C bf16 (shortcut)
    unsigned short* Zb    = Xb + (size_t)NROWS * C;        // NROWS*MID bf16
    unsigned short* w_all = Zb + (size_t)NROWS * MID;      // N_PTS*2560 bf16
    float* G   = (float*)(w_all + (size_t)N_PTS * 2560);   // N_PTS*192 f32
    float* scr = G + (size_t)N_PTS * 192;                  // N_PTS*8 f32

    k_proj  <<<dim3(NROWS / 128, 2), 256, 0, stream>>>(s_feats, W_proj, Hb);
    k_w     <<<N_PTS,                256, 0, stream>>>(s_pts, cg, nbr, w_all);
    k_cg    <<<N_PTS * 2,            256, 0, stream>>>(Hb, s_feats, w_all, nbr, Xb, scr);
    k_ff1   <<<NROWS / 128,          256, 0, stream>>>(Xb, scr, ln_w, ln_b, W_ff1, Zb);
    k_gate  <<<N_PTS / 16,           192, 0, stream>>>(Zb, W_gate, G);
    k_final <<<dim3(NROWS / 128, 2), 256, 0, stream>>>(Zb, G, W_ff2, Xb, out);
}

// Round 10
// 153.731 us; speedup vs baseline: 1.4886x; 1.4886x over previous
//
#include <hip/hip_runtime.h>
#include <hip/hip_bf16.h>

#define N_PTS  4096
#define NB     9
#define C      256
#define MID    64
#define KNBR   16
#define NROWS  (N_PTS * NB)          // 36864

typedef __attribute__((ext_vector_type(8))) short          short8;  // 8 bf16 (A/B frag)
typedef __attribute__((ext_vector_type(4))) float          f32x4;   // C/D frag
typedef __attribute__((ext_vector_type(2))) float          f32x2;
typedef __attribute__((ext_vector_type(4))) unsigned short ush4;
typedef __attribute__((ext_vector_type(8))) unsigned short ush8;

static __device__ __forceinline__ unsigned short f2bf(float f) {
    union { __hip_bfloat16 h; unsigned short u; } cv;
    cv.h = __float2bfloat16(f);          // RNE
    return cv.u;
}
static __device__ __forceinline__ float bf2f(unsigned short s) {
    union { unsigned u; float f; } v; v.u = ((unsigned)s) << 16;
    return v.f;
}
static __device__ __forceinline__ f32x2 bf2x2(unsigned u) {
    union { unsigned u; float f; } lo, hi;
    lo.u = u << 16;
    hi.u = u & 0xffff0000u;
    return (f32x2){lo.f, hi.f};
}
static __device__ __forceinline__ unsigned packbf(float a, float b) {
    return (unsigned)f2bf(a) | ((unsigned)f2bf(b) << 16);
}

// ---------------------------------------------------------------------------
// Kernel 1: h(bf16) = s_feats(f32) @ W_proj(f32); also emits sfb = bf16(s_feats)
// (written once, from blockIdx.y==0, reusing the already-staged A tile values).
#define LDK 40            // 32 + 8 pad (ushorts); row stride 80B, 16B aligned
__global__ __launch_bounds__(256) void k_proj(const float* __restrict__ A,
                                              const float* __restrict__ W,
                                              unsigned short* __restrict__ H,
                                              unsigned short* __restrict__ SFB) {
    __shared__ unsigned short As[128 * LDK];
    __shared__ unsigned short Bs[128 * LDK];
    const int tid = threadIdx.x;
    const int r0  = blockIdx.x * 128;
    const int n0  = blockIdx.y * 128;
    const bool emit_sfb = (blockIdx.y == 0);
    const int wave = tid >> 6, lane = tid & 63;
    const int wm = wave >> 1, wn = wave & 1;
    const int lr = lane & 15, lg = lane >> 4;

    f32x4 acc[4][4];
#pragma unroll
    for (int a = 0; a < 4; ++a)
#pragma unroll
        for (int b = 0; b < 4; ++b) acc[a][b] = (f32x4){0.f, 0.f, 0.f, 0.f};

    for (int k0 = 0; k0 < C; k0 += 32) {
        __syncthreads();
#pragma unroll
        for (int rep = 0; rep < 4; ++rep) {
            const int e   = rep * 256 + tid;      // float4 unit, 8 per row
            const int row = e >> 3;
            const int c4  = (e & 7) << 2;
            const float4 v = *reinterpret_cast<const float4*>(&A[(size_t)(r0 + row) * C + k0 + c4]);
            ush4 s = { f2bf(v.x), f2bf(v.y), f2bf(v.z), f2bf(v.w) };
            *reinterpret_cast<ush4*>(&As[row * LDK + c4]) = s;
            if (emit_sfb)
                *reinterpret_cast<ush4*>(&SFB[(size_t)(r0 + row) * C + k0 + c4]) = s;
        }
#pragma unroll
        for (int rep = 0; rep < 4; ++rep) {
            const int e = rep * 256 + tid;        // float4 unit, 32 per k-row
            const int k = e >> 5;
            const int j = (e & 31) << 2;
            const float4 v = *reinterpret_cast<const float4*>(&W[(size_t)(k0 + k) * C + n0 + j]);
            Bs[(j + 0) * LDK + k] = f2bf(v.x);
            Bs[(j + 1) * LDK + k] = f2bf(v.y);
            Bs[(j + 2) * LDK + k] = f2bf(v.z);
            Bs[(j + 3) * LDK + k] = f2bf(v.w);
        }
        __syncthreads();

        short8 af[4], bfr[4];
#pragma unroll
        for (int mf = 0; mf < 4; ++mf)
            af[mf] = *reinterpret_cast<const short8*>(&As[(wm * 64 + mf * 16 + lr) * LDK + lg * 8]);
#pragma unroll
        for (int nf = 0; nf < 4; ++nf)
            bfr[nf] = *reinterpret_cast<const short8*>(&Bs[(wn * 64 + nf * 16 + lr) * LDK + lg * 8]);
#pragma unroll
        for (int mf = 0; mf < 4; ++mf)
#pragma unroll
            for (int nf = 0; nf < 4; ++nf)
                acc[mf][nf] = __builtin_amdgcn_mfma_f32_16x16x32_bf16(af[mf], bfr[nf], acc[mf][nf], 0, 0, 0);
    }
#pragma unroll
    for (int mf = 0; mf < 4; ++mf)
#pragma unroll
        for (int nf = 0; nf < 4; ++nf) {
            const int col = n0 + wn * 64 + nf * 16 + lr;
#pragma unroll
            for (int r = 0; r < 4; ++r) {
                const int row = r0 + wm * 64 + mf * 16 + lg * 4 + r;
                H[(size_t)row * C + col] = f2bf(acc[mf][nf][r]);
            }
        }
}

// ---------------------------------------------------------------------------
// k_cg_ln helpers: gather one 32-ki chunk into 4 ush8 regs / stage to Bs.
static __device__ __forceinline__ void load_chunk(const unsigned short* __restrict__ Hb,
                                                  const int* idx_s, int ki, int s,
                                                  ush8& q0, ush8& q1, ush8& q2, ush8& q3) {
    const int kk = ki / 9;
    const int ii = ki - kk * 9;
    const unsigned short* hrow = Hb + (size_t)(idx_s[kk] * NB + ii) * C + s * 32;
    q0 = *reinterpret_cast<const ush8*>(hrow + 0);
    q1 = *reinterpret_cast<const ush8*>(hrow + 8);
    q2 = *reinterpret_cast<const ush8*>(hrow + 16);
    q3 = *reinterpret_cast<const ush8*>(hrow + 24);
}
static __device__ __forceinline__ void stage_chunk(unsigned short* Bs, int r, int s, int nrows,
                                                   ush8 q0, ush8 q1, ush8 q2, ush8 q3) {
    if (r < nrows) {
        const unsigned short* qe;
        qe = reinterpret_cast<const unsigned short*>(&q0);
#pragma unroll
        for (int e = 0; e < 8; ++e) Bs[(s * 32 + e) * 40 + r] = qe[e];
        qe = reinterpret_cast<const unsigned short*>(&q1);
#pragma unroll
        for (int e = 0; e < 8; ++e) Bs[(s * 32 + 8 + e) * 40 + r] = qe[e];
        qe = reinterpret_cast<const unsigned short*>(&q2);
#pragma unroll
        for (int e = 0; e < 8; ++e) Bs[(s * 32 + 16 + e) * 40 + r] = qe[e];
        qe = reinterpret_cast<const unsigned short*>(&q3);
#pragma unroll
        for (int e = 0; e < 8; ++e) Bs[(s * 32 + 24 + e) * 40 + r] = qe[e];
    }
}

// ---------------------------------------------------------------------------
// Kernel 2: CG contraction via MFMA + residual; LN stats only (apply in k_ff1).
// r8 skeleton (proven): one block (4 waves) per point, 5 chunks, Bs[256][40],
// wT[16][168] zero-padded, cg staged via Bs alias. New: 2-deep register
// prefetch (named slots qa*/qb*, statically rotated), sfb (bf16) residual read.
__global__ __launch_bounds__(256) void k_cg_ln(const unsigned short* __restrict__ Hb,
                                               const unsigned short* __restrict__ SFB,
                                               const float* __restrict__ pts,
                                               const float* __restrict__ cg,
                                               const int*   __restrict__ nbr,
                                               unsigned short* __restrict__ Xb,
                                               float* __restrict__ scr) {
    __shared__ unsigned short Bs[256 * 40];      // 20 KB; starts aliased as cg staging
    __shared__ unsigned short wT[16 * 168];      // 5.25 KB, A operand (zero-padded)
    __shared__ float sh_s[KNBR][NB];
    __shared__ int   idx_s[KNBR];
    __shared__ float red_s[2][4];

    float* const cg_s = reinterpret_cast<float*>(Bs);   // dead before 1st Bs write

    const int tid  = threadIdx.x;
    const int n    = blockIdx.x;
    const int wv   = tid >> 6;
    const int lane = tid & 63;
    const int g16  = lane >> 4;
    const int l16  = lane & 15;

    // ---- prologue: cg -> cg_s(=Bs), zero wT, SH + neighbor indices ----
    {
        unsigned* w32 = reinterpret_cast<unsigned*>(wT);
        for (int e = tid; e < (16 * 168) / 2; e += 256) w32[e] = 0u;
    }
    for (int e = tid; e < 729; e += 256) cg_s[e] = cg[e];
    if (tid < KNBR) {
        const int idx = nbr[n * KNBR + tid];
        idx_s[tid] = idx;
        const float px = pts[idx * 3 + 0] - pts[n * 3 + 0];
        const float py = pts[idx * 3 + 1] - pts[n * 3 + 1];
        const float pz = pts[idx * 3 + 2] - pts[n * 3 + 2];
        const float r  = sqrtf(px * px + py * py + pz * pz);
        const float iv = 1.f / (r + 1e-8f);
        const float dx = px * iv, dy = py * iv, dz = pz * iv;
        const float c1 = 0.4886025119029199f;
        const float c2 = 1.0925484305920792f;
        sh_s[tid][0] = 0.28209479177387814f;
        sh_s[tid][1] = c1 * dy;
        sh_s[tid][2] = c1 * dz;
        sh_s[tid][3] = c1 * dx;
        sh_s[tid][4] = c2 * dx * dy;
        sh_s[tid][5] = c2 * dy * dz;
        sh_s[tid][6] = 0.31539156525252005f * (3.f * dz * dz - 1.f);
        sh_s[tid][7] = c2 * dx * dz;
        sh_s[tid][8] = 0.5462742152960396f * (dx * dx - dy * dy);
    }
    __syncthreads();     // idx_s, sh_s, cg_s visible

    const int r = tid & 31;     // ki row within chunk
    const int s = tid >> 5;     // 32-channel segment

    // issue chunk 0 and chunk 1 gather loads NOW (2-deep pipeline head);
    // their ~900-cycle latency hides under the wT build below.
    ush8 qa0, qa1, qa2, qa3, qb0, qb1, qb2, qb3;
    load_chunk(Hb, idx_s, 0 * 32 + r, s, qa0, qa1, qa2, qa3);
    load_chunk(Hb, idx_s, 1 * 32 + r, s, qb0, qb1, qb2, qb3);

    // ---- build wT[o][ki] while loads are in flight ----
    for (int t = tid; t < 144 * 9; t += 256) {
        const int ki = t / 9;
        const int o  = t - ki * 9;
        const int kk = ki / 9;
        const int ii = ki - kk * 9;
        float sv = 0.f;
#pragma unroll
        for (int j = 0; j < 9; ++j) sv = fmaf(sh_s[kk][j], cg_s[ii * 81 + j * 9 + o], sv);
        wT[o * 168 + ki] = f2bf(sv);
    }

    f32x4 acc[4];
#pragma unroll
    for (int i = 0; i < 4; ++i) acc[i] = (f32x4){0.f, 0.f, 0.f, 0.f};

#define MFMA_STEP(cc)                                                                   \
    do {                                                                                \
        const short8 af = *reinterpret_cast<const short8*>(&wT[l16 * 168 + (cc) * 32 + g16 * 8]); \
        short8 bfr[4];                                                                  \
        _Pragma("unroll")                                                               \
        for (int ti = 0; ti < 4; ++ti)                                                  \
            bfr[ti] = *reinterpret_cast<const short8*>(&Bs[(wv * 64 + ti * 16 + l16) * 40 + g16 * 8]); \
        _Pragma("unroll")                                                               \
        for (int ti = 0; ti < 4; ++ti)                                                  \
            acc[ti] = __builtin_amdgcn_mfma_f32_16x16x32_bf16(af, bfr[ti], acc[ti], 0, 0, 0); \
    } while (0)

    // cc = 0  (slot A; prefetch chunk 2 into A)
    __syncthreads();                 // wT build + cg_s reads complete
    stage_chunk(Bs, r, s, 32, qa0, qa1, qa2, qa3);
    load_chunk(Hb, idx_s, 2 * 32 + r, s, qa0, qa1, qa2, qa3);
    __syncthreads();
    MFMA_STEP(0);
    // cc = 1  (slot B; prefetch chunk 3 into B)
    __syncthreads();
    stage_chunk(Bs, r, s, 32, qb0, qb1, qb2, qb3);
    load_chunk(Hb, idx_s, 3 * 32 + r, s, qb0, qb1, qb2, qb3);
    __syncthreads();
    MFMA_STEP(1);
    // cc = 2  (slot A; prefetch chunk 4 into A — only rows ki<144)
    __syncthreads();
    stage_chunk(Bs, r, s, 32, qa0, qa1, qa2, qa3);
    if (r < 16) load_chunk(Hb, idx_s, 4 * 32 + r, s, qa0, qa1, qa2, qa3);
    __syncthreads();
    MFMA_STEP(2);
    // cc = 3  (slot B)
    __syncthreads();
    stage_chunk(Bs, r, s, 32, qb0, qb1, qb2, qb3);
    __syncthreads();
    MFMA_STEP(3);
    // cc = 4  (slot A, 16 valid rows; cols 16..31 hold chunk-3 leftovers x wT=0)
    __syncthreads();
    stage_chunk(Bs, r, s, 16, qa0, qa1, qa2, qa3);
    __syncthreads();
    MFMA_STEP(4);
#undef MFMA_STEP

    // ---- epilogue: D -> LDS (scaled 1/K), residual(bf16 sfb), stats -> scr ----
    __syncthreads();                     // all Bs reads done before reuse
    float* const Dld = reinterpret_cast<float*>(Bs);   // [9][264] f32 = 9504 B
#pragma unroll
    for (int ti = 0; ti < 4; ++ti) {
        const int cgl = (wv * 4 + ti) * 16 + l16;
#pragma unroll
        for (int rr = 0; rr < 4; ++rr) {
            const int o = g16 * 4 + rr;  // m89: col=lane&15, row=(lane>>4)*4+reg
            if (o < 9) Dld[o * 264 + cgl] = acc[ti][rr] * (1.f / (float)KNBR);
        }
    }
    __syncthreads();

    if (tid < 128) {
        const int c = tid * 2;
        const unsigned* sfr = reinterpret_cast<const unsigned*>(SFB + (size_t)n * (NB * C));
        float2 xv[9];
#pragma unroll
        for (int i = 0; i < 9; ++i) {
            const f32x2 sv = bf2x2(sfr[i * 128 + tid]);
            xv[i].x = Dld[i * 264 + c]     + sv.x;
            xv[i].y = Dld[i * 264 + c + 1] + sv.y;
        }
        unsigned* xo = reinterpret_cast<unsigned*>(Xb + (size_t)n * (NB * C));
#pragma unroll
        for (int i = 0; i < 9; ++i) xo[i * 128 + tid] = packbf(xv[i].x, xv[i].y);

        float s0 = xv[0].x + xv[0].y;
        float s1 = xv[0].x * xv[0].x + xv[0].y * xv[0].y;
        float s2 = 0.f, s3 = 0.f;
#pragma unroll
        for (int o = 1; o < 4; ++o) s2 += xv[o].x * xv[o].x + xv[o].y * xv[o].y;
#pragma unroll
        for (int o = 4; o < 9; ++o) s3 += xv[o].x * xv[o].x + xv[o].y * xv[o].y;
#pragma unroll
        for (int off = 32; off >= 1; off >>= 1) {
            s0 += __shfl_xor(s0, off);
            s1 += __shfl_xor(s1, off);
            s2 += __shfl_xor(s2, off);
            s3 += __shfl_xor(s3, off);
        }
        if (lane == 0) {
            red_s[wv][0] = s0; red_s[wv][1] = s1;
            red_s[wv][2] = s2; red_s[wv][3] = s3;
        }
    }
    __syncthreads();
    if (tid == 0) {
        float* sp = scr + (size_t)n * 4;
        sp[0] = red_s[0][0] + red_s[1][0];
        sp[1] = red_s[0][1] + red_s[1][1];
        sp[2] = red_s[0][2] + red_s[1][2];
        sp[3] = red_s[0][3] + red_s[1][3];
    }
}

// ---------------------------------------------------------------------------
// Kernel 3: z(bf16) = LN(x) @ W_ff1.  LN fused into A-staging using scr stats.
__global__ __launch_bounds__(256) void k_ff1(const unsigned short* __restrict__ Xb,
                                             const float* __restrict__ scr,
                                             const float* __restrict__ ln_w,
                                             const float* __restrict__ ln_b,
                                             const float* __restrict__ W1,
                                             unsigned short* __restrict__ Zb) {
    __shared__ unsigned short As[128 * LDK];
    __shared__ unsigned short Bs[64 * LDK];
    const int tid = threadIdx.x;
    const int r0  = blockIdx.x * 128;
    const int wave = tid >> 6, lane = tid & 63;
    const int wm = wave >> 1, wn = wave & 1;
    const int lr = lane & 15, lg = lane >> 4;

    // per-rep row LN stats (rows fixed per thread across k0 chunks)
    float mu_[4], rv_[4];
    int   cls_[4];
#pragma unroll
    for (int rep = 0; rep < 4; ++rep) {
        const int row = r0 + ((rep * 256 + tid) >> 3);
        const int nn  = row / 9;
        const int ii  = row - nn * 9;
        const float* sp = scr + (size_t)nn * 4;
        const float a0 = sp[0], a1 = sp[1], a2 = sp[2], a3 = sp[3];
        if (ii == 0) {
            const float mu = a0 * (1.f / 256.f);
            mu_[rep] = mu;
            rv_[rep] = rsqrtf(a1 * (1.f / 256.f) - mu * mu + 1e-5f);
            cls_[rep] = 0;
        } else if (ii < 4) {
            mu_[rep] = 0.f; rv_[rep] = rsqrtf(a2 * (1.f / 768.f) + 1e-5f); cls_[rep] = 1;
        } else {
            mu_[rep] = 0.f; rv_[rep] = rsqrtf(a3 * (1.f / 1280.f) + 1e-5f); cls_[rep] = 2;
        }
    }

    f32x4 acc[4][2];
#pragma unroll
    for (int a = 0; a < 4; ++a) { acc[a][0] = (f32x4){0.f,0.f,0.f,0.f}; acc[a][1] = (f32x4){0.f,0.f,0.f,0.f}; }

    for (int k0 = 0; k0 < C; k0 += 32) {
        __syncthreads();
#pragma unroll
        for (int rep = 0; rep < 4; ++rep) {
            const int e   = rep * 256 + tid;     // ush4 unit, 8 per row
            const int row = e >> 3;
            const int c4  = (e & 7) << 2;
            const ush4 xq = *reinterpret_cast<const ush4*>(&Xb[(size_t)(r0 + row) * C + k0 + c4]);
            const float4 lw = *reinterpret_cast<const float4*>(&ln_w[cls_[rep] * C + k0 + c4]);
            const float mu = mu_[rep], rv = rv_[rep];
            float yx = (bf2f(xq.x) - mu) * rv * lw.x;
            float yy = (bf2f(xq.y) - mu) * rv * lw.y;
            float yz = (bf2f(xq.z) - mu) * rv * lw.z;
            float yw = (bf2f(xq.w) - mu) * rv * lw.w;
            if (cls_[rep] == 0) {
                const float4 lb = *reinterpret_cast<const float4*>(&ln_b[k0 + c4]);
                yx += lb.x; yy += lb.y; yz += lb.z; yw += lb.w;
            }
            ush4 s = { f2bf(yx), f2bf(yy), f2bf(yz), f2bf(yw) };
            *reinterpret_cast<ush4*>(&As[row * LDK + c4]) = s;
        }
#pragma unroll
        for (int rep = 0; rep < 2; ++rep) {
            const int e = rep * 256 + tid;       // float4 unit, 16 per k-row (64 n)
            const int k = e >> 4;
            const int j = (e & 15) << 2;
            const float4 v = *reinterpret_cast<const float4*>(&W1[(size_t)(k0 + k) * MID + j]);
            Bs[(j + 0) * LDK + k] = f2bf(v.x);
            Bs[(j + 1) * LDK + k] = f2bf(v.y);
            Bs[(j + 2) * LDK + k] = f2bf(v.z);
            Bs[(j + 3) * LDK + k] = f2bf(v.w);
        }
        __syncthreads();

        short8 af[4], bfr[2];
#pragma unroll
        for (int mf = 0; mf < 4; ++mf)
            af[mf] = *reinterpret_cast<const short8*>(&As[(wm * 64 + mf * 16 + lr) * LDK + lg * 8]);
#pragma unroll
        for (int nf = 0; nf < 2; ++nf)
            bfr[nf] = *reinterpret_cast<const short8*>(&Bs[(wn * 32 + nf * 16 + lr) * LDK + lg * 8]);
#pragma unroll
        for (int mf = 0; mf < 4; ++mf)
#pragma unroll
            for (int nf = 0; nf < 2; ++nf)
                acc[mf][nf] = __builtin_amdgcn_mfma_f32_16x16x32_bf16(af[mf], bfr[nf], acc[mf][nf], 0, 0, 0);
    }
#pragma unroll
    for (int mf = 0; mf < 4; ++mf)
#pragma unroll
        for (int nf = 0; nf < 2; ++nf) {
            const int col = wn * 32 + nf * 16 + lr;
#pragma unroll
            for (int r = 0; r < 4; ++r) {
                const int row = r0 + wm * 64 + mf * 16 + lg * 4 + r;
                Zb[(size_t)row * MID + col] = f2bf(acc[mf][nf][r]);
            }
        }
}

// ---------------------------------------------------------------------------
// Kernel 4: gate head. after = z0 @ W_gate; G[n][0:64]=silu, [64:192]=sigmoid.
__global__ __launch_bounds__(192) void k_gate(const unsigned short* __restrict__ Zb,
                                              const float* __restrict__ Wg,
                                              float* __restrict__ G) {
    __shared__ float wgs[64 * 192];
    __shared__ float z0s[16 * 64];
    const int tid = threadIdx.x;
    const int n0  = blockIdx.x * 16;

    for (int e = tid; e < 64 * 192; e += 192) wgs[e] = Wg[e];
    for (int e = tid; e < 16 * 64; e += 192) {
        const int r = e >> 6, m = e & 63;
        z0s[e] = bf2f(Zb[(size_t)(n0 + r) * (NB * MID) + m]);
    }
    __syncthreads();

    const int j = tid;
    for (int r = 0; r < 16; ++r) {
        float acc = 0.f;
        for (int m0 = 0; m0 < 64; m0 += 4) {
            const float4 zv = *reinterpret_cast<const float4*>(&z0s[r * 64 + m0]);
            acc = fmaf(zv.x, wgs[(m0 + 0) * 192 + j], acc);
            acc = fmaf(zv.y, wgs[(m0 + 1) * 192 + j], acc);
            acc = fmaf(zv.z, wgs[(m0 + 2) * 192 + j], acc);
            acc = fmaf(zv.w, wgs[(m0 + 3) * 192 + j], acc);
        }
        const float sig = 1.f / (1.f + expf(-acc));
        G[(size_t)(n0 + r) * 192 + j] = (j < 64) ? acc * sig : sig;
    }
}

// ---------------------------------------------------------------------------
// Kernel 5: out(f32) = gated(z) @ W_ff2 + x.  M=36864 K=64 N=256.
#define LDK64 72          // 64 + 8 pad; row stride 144B, 16B aligned
__global__ __launch_bounds__(256) void k_final(const unsigned short* __restrict__ Zb,
                                               const float* __restrict__ G,
                                               const float* __restrict__ W2,
                                               const unsigned short* __restrict__ Xb,
                                               float* __restrict__ OUT) {
    __shared__ unsigned short As[128 * LDK64];
    __shared__ unsigned short Bs[128 * LDK64];
    const int tid = threadIdx.x;
    const int r0  = blockIdx.x * 128;
    const int n0  = blockIdx.y * 128;
    const int wave = tid >> 6, lane = tid & 63;
    const int wm = wave >> 1, wn = wave & 1;
    const int lr = lane & 15, lg = lane >> 4;

    // stage A: gated-z rows (2 threads per row, 32 k each)
    {
        const int arow = tid >> 1;
        const int kh   = (tid & 1) * 32;
        const int grow = r0 + arow;
        const int nn   = grow / 9;
        const int ii   = grow - nn * 9;
        if (ii == 0) {
            const float* gp = &G[(size_t)nn * 192 + kh];
#pragma unroll
            for (int j = 0; j < 32; j += 4) {
                const float4 g = *reinterpret_cast<const float4*>(&gp[j]);
                ush4 s = { f2bf(g.x), f2bf(g.y), f2bf(g.z), f2bf(g.w) };
                *reinterpret_cast<ush4*>(&As[arow * LDK64 + kh + j]) = s;
            }
        } else {
            const float* gm = &G[(size_t)nn * 192 + ((ii < 4) ? 64 : 128) + kh];
            const unsigned short* zr = &Zb[(size_t)nn * (NB * MID) + ii * MID + kh];
#pragma unroll
            for (int j = 0; j < 32; j += 4) {
                const ush4 zv = *reinterpret_cast<const ush4*>(&zr[j]);
                const float4 g = *reinterpret_cast<const float4*>(&gm[j]);
                ush4 s = { f2bf(bf2f(zv.x) * g.x), f2bf(bf2f(zv.y) * g.y),
                           f2bf(bf2f(zv.z) * g.z), f2bf(bf2f(zv.w) * g.w) };
                *reinterpret_cast<ush4*>(&As[arow * LDK64 + kh + j]) = s;
            }
        }
    }
    // stage B: Bs[n][k] = W2[k][n0+n], full 64 x 128 tile
#pragma unroll
    for (int rep = 0; rep < 8; ++rep) {
        const int e = rep * 256 + tid;           // float4 unit, 32 per k-row
        const int k = e >> 5;
        const int j = (e & 31) << 2;
        const float4 v = *reinterpret_cast<const float4*>(&W2[(size_t)k * C + n0 + j]);
        Bs[(j + 0) * LDK64 + k] = f2bf(v.x);
        Bs[(j + 1) * LDK64 + k] = f2bf(v.y);
        Bs[(j + 2) * LDK64 + k] = f2bf(v.z);
        Bs[(j + 3) * LDK64 + k] = f2bf(v.w);
    }
    __syncthreads();

    f32x4 acc[4][4];
#pragma unroll
    for (int a = 0; a < 4; ++a)
#pragma unroll
        for (int b = 0; b < 4; ++b) acc[a][b] = (f32x4){0.f, 0.f, 0.f, 0.f};

#pragma unroll
    for (int ks = 0; ks < 2; ++ks) {
        short8 af[4], bfr[4];
#pragma unroll
        for (int mf = 0; mf < 4; ++mf)
            af[mf] = *reinterpret_cast<const short8*>(&As[(wm * 64 + mf * 16 + lr) * LDK64 + ks * 32 + lg * 8]);
#pragma unroll
        for (int nf = 0; nf < 4; ++nf)
            bfr[nf] = *reinterpret_cast<const short8*>(&Bs[(wn * 64 + nf * 16 + lr) * LDK64 + ks * 32 + lg * 8]);
#pragma unroll
        for (int mf = 0; mf < 4; ++mf)
#pragma unroll
            for (int nf = 0; nf < 4; ++nf)
                acc[mf][nf] = __builtin_amdgcn_mfma_f32_16x16x32_bf16(af[mf], bfr[nf], acc[mf][nf], 0, 0, 0);
    }

#pragma unroll
    for (int mf = 0; mf < 4; ++mf)
#pragma unroll
        for (int nf = 0; nf < 4; ++nf) {
            const int col = n0 + wn * 64 + nf * 16 + lr;
#pragma unroll
            for (int r = 0; r < 4; ++r) {
                const int row = r0 + wm * 64 + mf * 16 + lg * 4 + r;
                OUT[(size_t)row * C + col] = acc[mf][nf][r] + bf2f(Xb[(size_t)row * C + col]);
            }
        }
}

// ---------------------------------------------------------------------------
extern "C" void kernel_launch(void* const* d_in, const int* in_sizes, int n_in,
                              void* d_out, int out_size, void* d_ws, size_t ws_size,
                              hipStream_t stream) {
    const float* s_feats = (const float*)d_in[0];
    const float* s_pts   = (const float*)d_in[1];
    const float* cg      = (const float*)d_in[2];
    const float* W_proj  = (const float*)d_in[3];
    const float* ln_w    = (const float*)d_in[4];
    const float* ln_b    = (const float*)d_in[5];
    const float* W_ff1   = (const float*)d_in[6];
    const float* W_gate  = (const float*)d_in[7];
    const float* W_ff2   = (const float*)d_in[8];
    const int*   nbr     = (const int*)d_in[9];
    float* out = (float*)d_out;

    // workspace layout (~65 MB)
    unsigned short* Hb  = (unsigned short*)d_ws;           // NROWS*C bf16
    unsigned short* Xb  = Hb + (size_t)NROWS * C;          // NROWS*C bf16 (shortcut)
    unsigned short* Zb  = Xb + (size_t)NROWS * C;          // NROWS*MID bf16
    unsigned short* SFB = Zb + (size_t)NROWS * MID;        // NROWS*C bf16 (s_feats cast)
    float* G   = (float*)(SFB + (size_t)NROWS * C);        // N_PTS*192 f32
    float* scr = G + (size_t)N_PTS * 192;                  // N_PTS*4 f32

    k_proj  <<<dim3(NROWS / 128, 2), 256, 0, stream>>>(s_feats, W_proj, Hb, SFB);
    k_cg_ln <<<N_PTS,                256, 0, stream>>>(Hb, SFB, s_pts, cg, nbr, Xb, scr);
    k_ff1   <<<NROWS / 128,          256, 0, stream>>>(Xb, scr, ln_w, ln_b, W_ff1, Zb);
    k_gate  <<<N_PTS / 16,           192, 0, stream>>>(Zb, W_gate, G);
    k_final <<<dim3(NROWS / 128, 2), 256, 0, stream>>>(Zb, G, W_ff2, Xb, out);
}

// Round 11
// 117.635 us; speedup vs baseline: 1.9454x; 1.3068x over previous
//
#include <hip/hip_runtime.h>
#include <hip/hip_bf16.h>

#define N_PTS  4096
#define NB     9
#define C      256
#define MID    64
#define KNBR   16
#define NROWS  (N_PTS * NB)          // 36864

typedef __attribute__((ext_vector_type(8))) short          short8;  // 8 bf16 (A/B frag)
typedef __attribute__((ext_vector_type(4))) float          f32x4;   // C/D frag
typedef __attribute__((ext_vector_type(4))) unsigned short ush4;
typedef __attribute__((ext_vector_type(8))) unsigned short ush8;

static __device__ __forceinline__ unsigned short f2bf(float f) {
    union { __hip_bfloat16 h; unsigned short u; } cv;
    cv.h = __float2bfloat16(f);          // RNE
    return cv.u;
}
static __device__ __forceinline__ float bf2f(unsigned short s) {
    union { unsigned u; float f; } v; v.u = ((unsigned)s) << 16;
    return v.f;
}
static __device__ __forceinline__ unsigned packbf(float a, float b) {
    return (unsigned)f2bf(a) | ((unsigned)f2bf(b) << 16);
}

// ---------------------------------------------------------------------------
// Kernel 0: one-shot weight transposes to bf16 (out[n][k] = bf16(in[k][n])).
// blocks 0..63: W_proj(256x256); 64..79: W_ff1(256x64); 80..95: W_ff2(64x256).
__global__ __launch_bounds__(256) void k_prep(const float* __restrict__ Wp,
                                              const float* __restrict__ W1,
                                              const float* __restrict__ W2,
                                              unsigned short* __restrict__ Wpt,
                                              unsigned short* __restrict__ W1t,
                                              unsigned short* __restrict__ W2t) {
    __shared__ float T[32][33];
    const int b = blockIdx.x;
    const float* in; unsigned short* out; int K, N, kt, nt;
    if (b < 64)      { in = Wp; out = Wpt; K = 256; N = 256; kt = b >> 3;        nt = b & 7; }
    else if (b < 80) { in = W1; out = W1t; K = 256; N = 64;  kt = (b - 64) >> 1; nt = (b - 64) & 1; }
    else             { in = W2; out = W2t; K = 64;  N = 256; kt = (b - 80) >> 3; nt = (b - 80) & 7; }
    const int tx = threadIdx.x & 31;
    const int ty = threadIdx.x >> 5;   // 0..7
    const int k0 = kt * 32, n0 = nt * 32;
#pragma unroll
    for (int i = 0; i < 4; ++i)
        T[ty + i * 8][tx] = in[(size_t)(k0 + ty + i * 8) * N + n0 + tx];
    __syncthreads();
#pragma unroll
    for (int i = 0; i < 4; ++i)
        out[(size_t)(n0 + ty + i * 8) * K + k0 + tx] = f2bf(T[tx][ty + i * 8]);
}

// ---------------------------------------------------------------------------
// Kernel 1: h(bf16) = s_feats(f32) @ W_proj.  B from pre-transposed Wpt (bf16).
#define LDK 40            // 32 + 8 pad (ushorts); row stride 80B, 16B aligned
__global__ __launch_bounds__(256) void k_proj(const float* __restrict__ A,
                                              const unsigned short* __restrict__ Wpt,
                                              unsigned short* __restrict__ H) {
    __shared__ unsigned short As[128 * LDK];
    __shared__ unsigned short Bs[128 * LDK];
    const int tid = threadIdx.x;
    const int r0  = blockIdx.x * 128;
    const int n0  = blockIdx.y * 128;
    const int wave = tid >> 6, lane = tid & 63;
    const int wm = wave >> 1, wn = wave & 1;
    const int lr = lane & 15, lg = lane >> 4;

    f32x4 acc[4][4];
#pragma unroll
    for (int a = 0; a < 4; ++a)
#pragma unroll
        for (int b = 0; b < 4; ++b) acc[a][b] = (f32x4){0.f, 0.f, 0.f, 0.f};

    for (int k0 = 0; k0 < C; k0 += 32) {
        __syncthreads();
#pragma unroll
        for (int rep = 0; rep < 4; ++rep) {
            const int e   = rep * 256 + tid;      // float4 unit, 8 per row
            const int row = e >> 3;
            const int c4  = (e & 7) << 2;
            const float4 v = *reinterpret_cast<const float4*>(&A[(size_t)(r0 + row) * C + k0 + c4]);
            ush4 s = { f2bf(v.x), f2bf(v.y), f2bf(v.z), f2bf(v.w) };
            *reinterpret_cast<ush4*>(&As[row * LDK + c4]) = s;
        }
        // B: straight vector copy from Wpt[n][k] (no transpose, no cvt)
#pragma unroll
        for (int rep = 0; rep < 2; ++rep) {
            const int u   = rep * 256 + tid;      // ush8 unit, 4 per row
            const int row = u >> 2;
            const int seg = u & 3;
            *reinterpret_cast<ush8*>(&Bs[row * LDK + seg * 8]) =
                *reinterpret_cast<const ush8*>(&Wpt[(size_t)(n0 + row) * C + k0 + seg * 8]);
        }
        __syncthreads();

        short8 af[4], bfr[4];
#pragma unroll
        for (int mf = 0; mf < 4; ++mf)
            af[mf] = *reinterpret_cast<const short8*>(&As[(wm * 64 + mf * 16 + lr) * LDK + lg * 8]);
#pragma unroll
        for (int nf = 0; nf < 4; ++nf)
            bfr[nf] = *reinterpret_cast<const short8*>(&Bs[(wn * 64 + nf * 16 + lr) * LDK + lg * 8]);
#pragma unroll
        for (int mf = 0; mf < 4; ++mf)
#pragma unroll
            for (int nf = 0; nf < 4; ++nf)
                acc[mf][nf] = __builtin_amdgcn_mfma_f32_16x16x32_bf16(af[mf], bfr[nf], acc[mf][nf], 0, 0, 0);
    }
#pragma unroll
    for (int mf = 0; mf < 4; ++mf)
#pragma unroll
        for (int nf = 0; nf < 4; ++nf) {
            const int col = n0 + wn * 64 + nf * 16 + lr;
#pragma unroll
            for (int r = 0; r < 4; ++r) {
                const int row = r0 + wm * 64 + mf * 16 + lg * 4 + r;
                H[(size_t)row * C + col] = f2bf(acc[mf][nf][r]);
            }
        }
}

// ---------------------------------------------------------------------------
// k_cg_ln helpers: gather one 32-ki chunk into 4 ush8 regs / stage to Bs.
static __device__ __forceinline__ void load_chunk(const unsigned short* __restrict__ Hb,
                                                  const int* idx_s, int ki, int s,
                                                  ush8& q0, ush8& q1, ush8& q2, ush8& q3) {
    const int kk = ki / 9;
    const int ii = ki - kk * 9;
    const unsigned short* hrow = Hb + (size_t)(idx_s[kk] * NB + ii) * C + s * 32;
    q0 = *reinterpret_cast<const ush8*>(hrow + 0);
    q1 = *reinterpret_cast<const ush8*>(hrow + 8);
    q2 = *reinterpret_cast<const ush8*>(hrow + 16);
    q3 = *reinterpret_cast<const ush8*>(hrow + 24);
}
static __device__ __forceinline__ void stage_chunk(unsigned short* Bs, int r, int s, int nrows,
                                                   ush8 q0, ush8 q1, ush8 q2, ush8 q3) {
    if (r < nrows) {
        const unsigned short* qe;
        qe = reinterpret_cast<const unsigned short*>(&q0);
#pragma unroll
        for (int e = 0; e < 8; ++e) Bs[(s * 32 + e) * 40 + r] = qe[e];
        qe = reinterpret_cast<const unsigned short*>(&q1);
#pragma unroll
        for (int e = 0; e < 8; ++e) Bs[(s * 32 + 8 + e) * 40 + r] = qe[e];
        qe = reinterpret_cast<const unsigned short*>(&q2);
#pragma unroll
        for (int e = 0; e < 8; ++e) Bs[(s * 32 + 16 + e) * 40 + r] = qe[e];
        qe = reinterpret_cast<const unsigned short*>(&q3);
#pragma unroll
        for (int e = 0; e < 8; ++e) Bs[(s * 32 + 24 + e) * 40 + r] = qe[e];
    }
}

// ---------------------------------------------------------------------------
// Kernel 2: CG contraction via MFMA + residual; LN stats -> scr (applied in k_ff1).
// r8 skeleton + 2-deep register prefetch (r10, proven). fp32 s_feats residual.
__global__ __launch_bounds__(256) void k_cg_ln(const unsigned short* __restrict__ Hb,
                                               const float* __restrict__ s_feats,
                                               const float* __restrict__ pts,
                                               const float* __restrict__ cg,
                                               const int*   __restrict__ nbr,
                                               unsigned short* __restrict__ Xb,
                                               float* __restrict__ scr) {
    __shared__ unsigned short Bs[256 * 40];      // 20 KB; starts aliased as cg staging
    __shared__ unsigned short wT[16 * 168];      // 5.25 KB, A operand (zero-padded)
    __shared__ float sh_s[KNBR][NB];
    __shared__ int   idx_s[KNBR];
    __shared__ float red_s[2][4];

    float* const cg_s = reinterpret_cast<float*>(Bs);   // dead before 1st Bs write

    const int tid  = threadIdx.x;
    const int n    = blockIdx.x;
    const int wv   = tid >> 6;
    const int lane = tid & 63;
    const int g16  = lane >> 4;
    const int l16  = lane & 15;

    // ---- prologue: cg -> cg_s(=Bs), zero wT, SH + neighbor indices ----
    {
        unsigned* w32 = reinterpret_cast<unsigned*>(wT);
        for (int e = tid; e < (16 * 168) / 2; e += 256) w32[e] = 0u;
    }
    for (int e = tid; e < 729; e += 256) cg_s[e] = cg[e];
    if (tid < KNBR) {
        const int idx = nbr[n * KNBR + tid];
        idx_s[tid] = idx;
        const float px = pts[idx * 3 + 0] - pts[n * 3 + 0];
        const float py = pts[idx * 3 + 1] - pts[n * 3 + 1];
        const float pz = pts[idx * 3 + 2] - pts[n * 3 + 2];
        const float r  = sqrtf(px * px + py * py + pz * pz);
        const float iv = 1.f / (r + 1e-8f);
        const float dx = px * iv, dy = py * iv, dz = pz * iv;
        const float c1 = 0.4886025119029199f;
        const float c2 = 1.0925484305920792f;
        sh_s[tid][0] = 0.28209479177387814f;
        sh_s[tid][1] = c1 * dy;
        sh_s[tid][2] = c1 * dz;
        sh_s[tid][3] = c1 * dx;
        sh_s[tid][4] = c2 * dx * dy;
        sh_s[tid][5] = c2 * dy * dz;
        sh_s[tid][6] = 0.31539156525252005f * (3.f * dz * dz - 1.f);
        sh_s[tid][7] = c2 * dx * dz;
        sh_s[tid][8] = 0.5462742152960396f * (dx * dx - dy * dy);
    }
    __syncthreads();     // idx_s, sh_s, cg_s visible

    const int r = tid & 31;     // ki row within chunk
    const int s = tid >> 5;     // 32-channel segment

    // issue chunk 0 and chunk 1 gather loads NOW (2-deep pipeline head)
    ush8 qa0, qa1, qa2, qa3, qb0, qb1, qb2, qb3;
    load_chunk(Hb, idx_s, 0 * 32 + r, s, qa0, qa1, qa2, qa3);
    load_chunk(Hb, idx_s, 1 * 32 + r, s, qb0, qb1, qb2, qb3);

    // ---- build wT[o][ki] while loads are in flight ----
    for (int t = tid; t < 144 * 9; t += 256) {
        const int ki = t / 9;
        const int o  = t - ki * 9;
        const int kk = ki / 9;
        const int ii = ki - kk * 9;
        float sv = 0.f;
#pragma unroll
        for (int j = 0; j < 9; ++j) sv = fmaf(sh_s[kk][j], cg_s[ii * 81 + j * 9 + o], sv);
        wT[o * 168 + ki] = f2bf(sv);
    }

    f32x4 acc[4];
#pragma unroll
    for (int i = 0; i < 4; ++i) acc[i] = (f32x4){0.f, 0.f, 0.f, 0.f};

#define MFMA_STEP(cc)                                                                   \
    do {                                                                                \
        const short8 af = *reinterpret_cast<const short8*>(&wT[l16 * 168 + (cc) * 32 + g16 * 8]); \
        short8 bfr[4];                                                                  \
        _Pragma("unroll")                                                               \
        for (int ti = 0; ti < 4; ++ti)                                                  \
            bfr[ti] = *reinterpret_cast<const short8*>(&Bs[(wv * 64 + ti * 16 + l16) * 40 + g16 * 8]); \
        _Pragma("unroll")                                                               \
        for (int ti = 0; ti < 4; ++ti)                                                  \
            acc[ti] = __builtin_amdgcn_mfma_f32_16x16x32_bf16(af, bfr[ti], acc[ti], 0, 0, 0); \
    } while (0)

    // cc = 0  (slot A; prefetch chunk 2 into A)
    __syncthreads();                 // wT build + cg_s reads complete
    stage_chunk(Bs, r, s, 32, qa0, qa1, qa2, qa3);
    load_chunk(Hb, idx_s, 2 * 32 + r, s, qa0, qa1, qa2, qa3);
    __syncthreads();
    MFMA_STEP(0);
    // cc = 1  (slot B; prefetch chunk 3 into B)
    __syncthreads();
    stage_chunk(Bs, r, s, 32, qb0, qb1, qb2, qb3);
    load_chunk(Hb, idx_s, 3 * 32 + r, s, qb0, qb1, qb2, qb3);
    __syncthreads();
    MFMA_STEP(1);
    // cc = 2  (slot A; prefetch chunk 4 into A — only rows ki<144)
    __syncthreads();
    stage_chunk(Bs, r, s, 32, qa0, qa1, qa2, qa3);
    if (r < 16) load_chunk(Hb, idx_s, 4 * 32 + r, s, qa0, qa1, qa2, qa3);
    __syncthreads();
    MFMA_STEP(2);
    // cc = 3  (slot B)
    __syncthreads();
    stage_chunk(Bs, r, s, 32, qb0, qb1, qb2, qb3);
    __syncthreads();
    MFMA_STEP(3);
    // cc = 4  (slot A, 16 valid rows; cols 16..31 hold chunk-3 leftovers x wT=0)
    __syncthreads();
    stage_chunk(Bs, r, s, 16, qa0, qa1, qa2, qa3);
    __syncthreads();
    MFMA_STEP(4);
#undef MFMA_STEP

    // ---- epilogue: D -> LDS (scaled 1/K), residual (fp32), stats -> scr ----
    __syncthreads();                     // all Bs reads done before reuse
    float* const Dld = reinterpret_cast<float*>(Bs);   // [9][264] f32 = 9504 B
#pragma unroll
    for (int ti = 0; ti < 4; ++ti) {
        const int cgl = (wv * 4 + ti) * 16 + l16;
#pragma unroll
        for (int rr = 0; rr < 4; ++rr) {
            const int o = g16 * 4 + rr;  // m89: col=lane&15, row=(lane>>4)*4+reg
            if (o < 9) Dld[o * 264 + cgl] = acc[ti][rr] * (1.f / (float)KNBR);
        }
    }
    __syncthreads();

    if (tid < 128) {
        const int c = tid * 2;
        const float* sf = s_feats + (size_t)n * (NB * C) + c;
        float2 xv[9];
#pragma unroll
        for (int i = 0; i < 9; ++i) {
            const float2 sv = *reinterpret_cast<const float2*>(&sf[(size_t)i * C]);
            xv[i].x = Dld[i * 264 + c]     + sv.x;
            xv[i].y = Dld[i * 264 + c + 1] + sv.y;
        }
        unsigned* xo = reinterpret_cast<unsigned*>(Xb + (size_t)n * (NB * C));
#pragma unroll
        for (int i = 0; i < 9; ++i) xo[i * 128 + tid] = packbf(xv[i].x, xv[i].y);

        float s0 = xv[0].x + xv[0].y;
        float s1 = xv[0].x * xv[0].x + xv[0].y * xv[0].y;
        float s2 = 0.f, s3 = 0.f;
#pragma unroll
        for (int o = 1; o < 4; ++o) s2 += xv[o].x * xv[o].x + xv[o].y * xv[o].y;
#pragma unroll
        for (int o = 4; o < 9; ++o) s3 += xv[o].x * xv[o].x + xv[o].y * xv[o].y;
#pragma unroll
        for (int off = 32; off >= 1; off >>= 1) {
            s0 += __shfl_xor(s0, off);
            s1 += __shfl_xor(s1, off);
            s2 += __shfl_xor(s2, off);
            s3 += __shfl_xor(s3, off);
        }
        if (lane == 0) {
            red_s[wv][0] = s0; red_s[wv][1] = s1;
            red_s[wv][2] = s2; red_s[wv][3] = s3;
        }
    }
    __syncthreads();
    if (tid == 0) {
        float* sp = scr + (size_t)n * 4;
        sp[0] = red_s[0][0] + red_s[1][0];
        sp[1] = red_s[0][1] + red_s[1][1];
        sp[2] = red_s[0][2] + red_s[1][2];
        sp[3] = red_s[0][3] + red_s[1][3];
    }
}

// ---------------------------------------------------------------------------
// Kernel 3: z(bf16) = LN(x) @ W_ff1.  LN fused into A-staging; B from W1t.
__global__ __launch_bounds__(256) void k_ff1(const unsigned short* __restrict__ Xb,
                                             const float* __restrict__ scr,
                                             const float* __restrict__ ln_w,
                                             const float* __restrict__ ln_b,
                                             const unsigned short* __restrict__ W1t,
                                             unsigned short* __restrict__ Zb) {
    __shared__ unsigned short As[128 * LDK];
    __shared__ unsigned short Bs[64 * LDK];
    const int tid = threadIdx.x;
    const int r0  = blockIdx.x * 128;
    const int wave = tid >> 6, lane = tid & 63;
    const int wm = wave >> 1, wn = wave & 1;
    const int lr = lane & 15, lg = lane >> 4;

    // per-rep row LN stats (rows fixed per thread across k0 chunks)
    float mu_[4], rv_[4];
    int   cls_[4];
#pragma unroll
    for (int rep = 0; rep < 4; ++rep) {
        const int row = r0 + ((rep * 256 + tid) >> 3);
        const int nn  = row / 9;
        const int ii  = row - nn * 9;
        const float* sp = scr + (size_t)nn * 4;
        const float a0 = sp[0], a1 = sp[1], a2 = sp[2], a3 = sp[3];
        if (ii == 0) {
            const float mu = a0 * (1.f / 256.f);
            mu_[rep] = mu;
            rv_[rep] = rsqrtf(a1 * (1.f / 256.f) - mu * mu + 1e-5f);
            cls_[rep] = 0;
        } else if (ii < 4) {
            mu_[rep] = 0.f; rv_[rep] = rsqrtf(a2 * (1.f / 768.f) + 1e-5f); cls_[rep] = 1;
        } else {
            mu_[rep] = 0.f; rv_[rep] = rsqrtf(a3 * (1.f / 1280.f) + 1e-5f); cls_[rep] = 2;
        }
    }

    f32x4 acc[4][2];
#pragma unroll
    for (int a = 0; a < 4; ++a) { acc[a][0] = (f32x4){0.f,0.f,0.f,0.f}; acc[a][1] = (f32x4){0.f,0.f,0.f,0.f}; }

    for (int k0 = 0; k0 < C; k0 += 32) {
        __syncthreads();
#pragma unroll
        for (int rep = 0; rep < 4; ++rep) {
            const int e   = rep * 256 + tid;     // ush4 unit, 8 per row
            const int row = e >> 3;
            const int c4  = (e & 7) << 2;
            const ush4 xq = *reinterpret_cast<const ush4*>(&Xb[(size_t)(r0 + row) * C + k0 + c4]);
            const float4 lw = *reinterpret_cast<const float4*>(&ln_w[cls_[rep] * C + k0 + c4]);
            const float mu = mu_[rep], rv = rv_[rep];
            float yx = (bf2f(xq.x) - mu) * rv * lw.x;
            float yy = (bf2f(xq.y) - mu) * rv * lw.y;
            float yz = (bf2f(xq.z) - mu) * rv * lw.z;
            float yw = (bf2f(xq.w) - mu) * rv * lw.w;
            if (cls_[rep] == 0) {
                const float4 lb = *reinterpret_cast<const float4*>(&ln_b[k0 + c4]);
                yx += lb.x; yy += lb.y; yz += lb.z; yw += lb.w;
            }
            ush4 s = { f2bf(yx), f2bf(yy), f2bf(yz), f2bf(yw) };
            *reinterpret_cast<ush4*>(&As[row * LDK + c4]) = s;
        }
        // B: straight vector copy from W1t[m][k]
        {
            const int row = tid >> 2;
            const int seg = tid & 3;
            *reinterpret_cast<ush8*>(&Bs[row * LDK + seg * 8]) =
                *reinterpret_cast<const ush8*>(&W1t[(size_t)row * C + k0 + seg * 8]);
        }
        __syncthreads();

        short8 af[4], bfr[2];
#pragma unroll
        for (int mf = 0; mf < 4; ++mf)
            af[mf] = *reinterpret_cast<const short8*>(&As[(wm * 64 + mf * 16 + lr) * LDK + lg * 8]);
#pragma unroll
        for (int nf = 0; nf < 2; ++nf)
            bfr[nf] = *reinterpret_cast<const short8*>(&Bs[(wn * 32 + nf * 16 + lr) * LDK + lg * 8]);
#pragma unroll
        for (int mf = 0; mf < 4; ++mf)
#pragma unroll
            for (int nf = 0; nf < 2; ++nf)
                acc[mf][nf] = __builtin_amdgcn_mfma_f32_16x16x32_bf16(af[mf], bfr[nf], acc[mf][nf], 0, 0, 0);
    }
#pragma unroll
    for (int mf = 0; mf < 4; ++mf)
#pragma unroll
        for (int nf = 0; nf < 2; ++nf) {
            const int col = wn * 32 + nf * 16 + lr;
#pragma unroll
            for (int r = 0; r < 4; ++r) {
                const int row = r0 + wm * 64 + mf * 16 + lg * 4 + r;
                Zb[(size_t)row * MID + col] = f2bf(acc[mf][nf][r]);
            }
        }
}

// ---------------------------------------------------------------------------
// Kernel 4: gate head. after = z0 @ W_gate; G[n][0:64]=silu, [64:192]=sigmoid.
__global__ __launch_bounds__(192) void k_gate(const unsigned short* __restrict__ Zb,
                                              const float* __restrict__ Wg,
                                              float* __restrict__ G) {
    __shared__ float wgs[64 * 192];
    __shared__ float z0s[16 * 64];
    const int tid = threadIdx.x;
    const int n0  = blockIdx.x * 16;

    for (int e = tid; e < 64 * 192; e += 192) wgs[e] = Wg[e];
    for (int e = tid; e < 16 * 64; e += 192) {
        const int r = e >> 6, m = e & 63;
        z0s[e] = bf2f(Zb[(size_t)(n0 + r) * (NB * MID) + m]);
    }
    __syncthreads();

    const int j = tid;
    for (int r = 0; r < 16; ++r) {
        float acc = 0.f;
        for (int m0 = 0; m0 < 64; m0 += 4) {
            const float4 zv = *reinterpret_cast<const float4*>(&z0s[r * 64 + m0]);
            acc = fmaf(zv.x, wgs[(m0 + 0) * 192 + j], acc);
            acc = fmaf(zv.y, wgs[(m0 + 1) * 192 + j], acc);
            acc = fmaf(zv.z, wgs[(m0 + 2) * 192 + j], acc);
            acc = fmaf(zv.w, wgs[(m0 + 3) * 192 + j], acc);
        }
        const float sig = 1.f / (1.f + expf(-acc));
        G[(size_t)(n0 + r) * 192 + j] = (j < 64) ? acc * sig : sig;
    }
}

// ---------------------------------------------------------------------------
// Kernel 5: out(f32) = gated(z) @ W_ff2 + x.  B from pre-transposed W2t (bf16).
#define LDK64 72          // 64 + 8 pad; row stride 144B, 16B aligned
__global__ __launch_bounds__(256) void k_final(const unsigned short* __restrict__ Zb,
                                               const float* __restrict__ G,
                                               const unsigned short* __restrict__ W2t,
                                               const unsigned short* __restrict__ Xb,
                                               float* __restrict__ OUT) {
    __shared__ unsigned short As[128 * LDK64];
    __shared__ unsigned short Bs[128 * LDK64];
    const int tid = threadIdx.x;
    const int r0  = blockIdx.x * 128;
    const int n0  = blockIdx.y * 128;
    const int wave = tid >> 6, lane = tid & 63;
    const int wm = wave >> 1, wn = wave & 1;
    const int lr = lane & 15, lg = lane >> 4;

    // stage A: gated-z rows (2 threads per row, 32 k each)
    {
        const int arow = tid >> 1;
        const int kh   = (tid & 1) * 32;
        const int grow = r0 + arow;
        const int nn   = grow / 9;
        const int ii   = grow - nn * 9;
        if (ii == 0) {
            const float* gp = &G[(size_t)nn * 192 + kh];
#pragma unroll
            for (int j = 0; j < 32; j += 4) {
                const float4 g = *reinterpret_cast<const float4*>(&gp[j]);
                ush4 s = { f2bf(g.x), f2bf(g.y), f2bf(g.z), f2bf(g.w) };
                *reinterpret_cast<ush4*>(&As[arow * LDK64 + kh + j]) = s;
            }
        } else {
            const float* gm = &G[(size_t)nn * 192 + ((ii < 4) ? 64 : 128) + kh];
            const unsigned short* zr = &Zb[(size_t)nn * (NB * MID) + ii * MID + kh];
#pragma unroll
            for (int j = 0; j < 32; j += 4) {
                const ush4 zv = *reinterpret_cast<const ush4*>(&zr[j]);
                const float4 g = *reinterpret_cast<const float4*>(&gm[j]);
                ush4 s = { f2bf(bf2f(zv.x) * g.x), f2bf(bf2f(zv.y) * g.y),
                           f2bf(bf2f(zv.z) * g.z), f2bf(bf2f(zv.w) * g.w) };
                *reinterpret_cast<ush4*>(&As[arow * LDK64 + kh + j]) = s;
            }
        }
    }
    // stage B: straight vector copy from W2t[c][m]
#pragma unroll
    for (int rep = 0; rep < 4; ++rep) {
        const int u   = rep * 256 + tid;         // ush8 unit, 8 per row
        const int row = u >> 3;
        const int seg = u & 7;
        *reinterpret_cast<ush8*>(&Bs[row * LDK64 + seg * 8]) =
            *reinterpret_cast<const ush8*>(&W2t[(size_t)(n0 + row) * MID + seg * 8]);
    }
    __syncthreads();

    f32x4 acc[4][4];
#pragma unroll
    for (int a = 0; a < 4; ++a)
#pragma unroll
        for (int b = 0; b < 4; ++b) acc[a][b] = (f32x4){0.f, 0.f, 0.f, 0.f};

#pragma unroll
    for (int ks = 0; ks < 2; ++ks) {
        short8 af[4], bfr[4];
#pragma unroll
        for (int mf = 0; mf < 4; ++mf)
            af[mf] = *reinterpret_cast<const short8*>(&As[(wm * 64 + mf * 16 + lr) * LDK64 + ks * 32 + lg * 8]);
#pragma unroll
        for (int nf = 0; nf < 4; ++nf)
            bfr[nf] = *reinterpret_cast<const short8*>(&Bs[(wn * 64 + nf * 16 + lr) * LDK64 + ks * 32 + lg * 8]);
#pragma unroll
        for (int mf = 0; mf < 4; ++mf)
#pragma unroll
            for (int nf = 0; nf < 4; ++nf)
                acc[mf][nf] = __builtin_amdgcn_mfma_f32_16x16x32_bf16(af[mf], bfr[nf], acc[mf][nf], 0, 0, 0);
    }

#pragma unroll
    for (int mf = 0; mf < 4; ++mf)
#pragma unroll
        for (int nf = 0; nf < 4; ++nf) {
            const int col = n0 + wn * 64 + nf * 16 + lr;
#pragma unroll
            for (int r = 0; r < 4; ++r) {
                const int row = r0 + wm * 64 + mf * 16 + lg * 4 + r;
                OUT[(size_t)row * C + col] = acc[mf][nf][r] + bf2f(Xb[(size_t)row * C + col]);
            }
        }
}

// ---------------------------------------------------------------------------
extern "C" void kernel_launch(void* const* d_in, const int* in_sizes, int n_in,
                              void* d_out, int out_size, void* d_ws, size_t ws_size,
                              hipStream_t stream) {
    const float* s_feats = (const float*)d_in[0];
    const float* s_pts   = (const float*)d_in[1];
    const float* cg      = (const float*)d_in[2];
    const float* W_proj  = (const float*)d_in[3];
    const float* ln_w    = (const float*)d_in[4];
    const float* ln_b    = (const float*)d_in[5];
    const float* W_ff1   = (const float*)d_in[6];
    const float* W_gate  = (const float*)d_in[7];
    const float* W_ff2   = (const float*)d_in[8];
    const int*   nbr     = (const int*)d_in[9];
    float* out = (float*)d_out;

    // workspace layout (~46 MB)
    unsigned short* Hb  = (unsigned short*)d_ws;           // NROWS*C bf16
    unsigned short* Xb  = Hb + (size_t)NROWS * C;          // NROWS*C bf16 (shortcut)
    unsigned short* Zb  = Xb + (size_t)NROWS * C;          // NROWS*MID bf16
    unsigned short* Wpt = Zb + (size_t)NROWS * MID;        // 256*256 bf16
    unsigned short* W1t = Wpt + 256 * 256;                 // 64*256 bf16
    unsigned short* W2t = W1t + 64 * 256;                  // 256*64 bf16
    float* G   = (float*)(W2t + 256 * 64);                 // N_PTS*192 f32
    float* scr = G + (size_t)N_PTS * 192;                  // N_PTS*4 f32

    k_prep  <<<96,                   256, 0, stream>>>(W_proj, W_ff1, W_ff2, Wpt, W1t, W2t);
    k_proj  <<<dim3(NROWS / 128, 2), 256, 0, stream>>>(s_feats, Wpt, Hb);
    k_cg_ln <<<N_PTS,                256, 0, stream>>>(Hb, s_feats, s_pts, cg, nbr, Xb, scr);
    k_ff1   <<<NROWS / 128,          256, 0, stream>>>(Xb, scr, ln_w, ln_b, W1t, Zb);
    k_gate  <<<N_PTS / 16,           192, 0, stream>>>(Zb, W_gate, G);
    k_final <<<dim3(NROWS / 128, 2), 256, 0, stream>>>(Zb, G, W2t, Xb, out);
}